// Round 1
// baseline (415.857 us; speedup 1.0000x reference)
//
#include <hip/hip_runtime.h>

typedef _Float16 f16;
typedef _Float16 f16x4 __attribute__((ext_vector_type(4)));
typedef _Float16 f16x8 __attribute__((ext_vector_type(8)));
typedef float    f32x4 __attribute__((ext_vector_type(4)));

#define DEV static __device__ __forceinline__

DEV f32x4 mfma16(f16x8 a, f16x8 b, f32x4 c) {
    return __builtin_amdgcn_mfma_f32_16x16x32_f16(a, b, c, 0, 0, 0);
}

// ---------------------------------------------------------------- constants
// B=4, S=1024, D=768, H=12, DH=64, R=129 (padded to 160 for k-steps of 32)

// ---------------------------------------------------------------- convert
struct ConvArgs {
    const float* src[8];
    f16*         dst[8];
};

__global__ __launch_bounds__(256) void k_convert(ConvArgs a) {
    // element counts /4: q,k,v = 786432 each; 4 weights = 147456 each; embK = 24768
    const int seg[9] = {0, 786432, 1572864, 2359296, 2506752, 2654208,
                        2801664, 2949120, 2973888};
    for (int i = blockIdx.x * 256 + threadIdx.x; i < 2973888; i += gridDim.x * 256) {
        int s = 0;
        while (i >= seg[s + 1]) s++;
        const int j = i - seg[s];
        const float4 v = ((const float4*)a.src[s])[j];
        f16x4 o;
        o[0] = (f16)v.x; o[1] = (f16)v.y; o[2] = (f16)v.z; o[3] = (f16)v.w;
        ((f16x4*)a.dst[s])[j] = o;
    }
}

// embVt[h][dh][r] = embV[r, h*64+dh] for r<129 else 0   (12*64*160 elements)
__global__ __launch_bounds__(256) void k_embvt(const float* __restrict__ embV,
                                               f16* __restrict__ dst) {
    const int idx = blockIdx.x * 256 + threadIdx.x;
    if (idx >= 12 * 64 * 160) return;
    const int r  = idx % 160;
    const int dh = (idx / 160) % 64;
    const int h  = idx / (160 * 64);
    float v = 0.f;
    if (r < 129) v = embV[r * 768 + h * 64 + dh];
    dst[idx] = (f16)v;
}

// ---------------------------------------------------------------- QKV GEMM
// C[m][n] = sum_k X[m][k]*W[n][k] + bias[n] ; fused Q/K/V by blockIdx.y/6.
// 128x128 tile, BK=32, 256 threads = 4 waves, each wave a 64x64 sub-tile.
// LDS rows padded 32->40 f16 (80 B, 16B-multiple, 2-way max bank aliasing).
constexpr int LDA = 40;

__global__ __launch_bounds__(256) void k_gemm_qkv(
    const f16* __restrict__ xq, const f16* __restrict__ xk, const f16* __restrict__ xv,
    const f16* __restrict__ wq, const f16* __restrict__ wk, const f16* __restrict__ wv,
    const float* __restrict__ bq, const float* __restrict__ bk, const float* __restrict__ bv,
    f16* __restrict__ Qh, f16* __restrict__ Kh, f16* __restrict__ Vt) {
    __shared__ __align__(16) f16 As[128 * LDA];
    __shared__ __align__(16) f16 Bs[128 * LDA];

    const int t  = blockIdx.y / 6;           // 0:Q 1:K 2:V
    const int n0 = (blockIdx.y % 6) * 128;   // within 768
    const int m0 = blockIdx.x * 128;
    const f16*   X    = (t == 0) ? xq : (t == 1) ? xk : xv;
    const f16*   W    = (t == 0) ? wq : (t == 1) ? wk : wv;
    const float* bias = (t == 0) ? bq : (t == 1) ? bk : bv;

    const int tid = threadIdx.x;
    const int w = tid >> 6, l = tid & 63, quad = l >> 4, l16 = l & 15;
    const int wr = w >> 1, wc = w & 1;

    const int srow = 32 * w + (l >> 2);      // staging row for this lane
    const int scol = (l & 3) * 8;            // f16 offset within BK
    const f16* gA = X + (m0 + srow) * 768 + scol;
    const f16* gB = W + (n0 + srow) * 768 + scol;

    f32x4 acc[4][4] = {};

    for (int k0 = 0; k0 < 768; k0 += 32) {
        const f16x8 va0 = *(const f16x8*)(gA + k0);
        const f16x8 va1 = *(const f16x8*)(gA + k0 + 16 * 768);
        const f16x8 vb0 = *(const f16x8*)(gB + k0);
        const f16x8 vb1 = *(const f16x8*)(gB + k0 + 16 * 768);
        __syncthreads();  // previous iteration's readers done
        *(f16x8*)(As + srow * LDA + scol)        = va0;
        *(f16x8*)(As + (srow + 16) * LDA + scol) = va1;
        *(f16x8*)(Bs + srow * LDA + scol)        = vb0;
        *(f16x8*)(Bs + (srow + 16) * LDA + scol) = vb1;
        __syncthreads();
        f16x8 af[4], bf[4];
#pragma unroll
        for (int i = 0; i < 4; i++)
            af[i] = *(const f16x8*)(As + (wr * 64 + i * 16 + l16) * LDA + quad * 8);
#pragma unroll
        for (int i = 0; i < 4; i++)
            bf[i] = *(const f16x8*)(Bs + (wc * 64 + i * 16 + l16) * LDA + quad * 8);
#pragma unroll
        for (int i = 0; i < 4; i++)
#pragma unroll
            for (int j = 0; j < 4; j++)
                acc[i][j] = mfma16(af[i], bf[j], acc[i][j]);
    }

    // epilogue: C/D layout col=lane&15, row=quad*4+reg
#pragma unroll
    for (int j = 0; j < 4; j++) {
        const int   nj = n0 + wc * 64 + j * 16 + l16;  // 0..767
        const float bb = bias[nj];
        const int   h = nj >> 6, dh = nj & 63;
#pragma unroll
        for (int i = 0; i < 4; i++) {
            const int mb = m0 + wr * 64 + i * 16 + quad * 4;
            const int b = mb >> 10, s = mb & 1023;
            if (t < 2) {
                f16* dst = (t == 0) ? Qh : Kh;
                const int base = ((b * 12 + h) * 1024 + s) * 64 + dh;
#pragma unroll
                for (int r = 0; r < 4; r++)
                    dst[base + r * 64] = (f16)(acc[i][j][r] + bb);
            } else {
                f16x4 pk;
#pragma unroll
                for (int r = 0; r < 4; r++) pk[r] = (f16)(acc[i][j][r] + bb);
                // V transposed: Vt[((b*12+h)*64+dh)*1024 + s], 4 consecutive s
                *(f16x4*)(Vt + ((b * 12 + h) * 64 + dh) * 1024 + s) = pk;
            }
        }
    }
}

// ---------------------------------------------------------------- out GEMM
__global__ __launch_bounds__(256) void k_gemm_out(
    const f16* __restrict__ X, const f16* __restrict__ W,
    const float* __restrict__ bias, float* __restrict__ out) {
    __shared__ __align__(16) f16 As[128 * LDA];
    __shared__ __align__(16) f16 Bs[128 * LDA];

    const int n0 = blockIdx.y * 128;
    const int m0 = blockIdx.x * 128;
    const int tid = threadIdx.x;
    const int w = tid >> 6, l = tid & 63, quad = l >> 4, l16 = l & 15;
    const int wr = w >> 1, wc = w & 1;

    const int srow = 32 * w + (l >> 2);
    const int scol = (l & 3) * 8;
    const f16* gA = X + (m0 + srow) * 768 + scol;
    const f16* gB = W + (n0 + srow) * 768 + scol;

    f32x4 acc[4][4] = {};

    for (int k0 = 0; k0 < 768; k0 += 32) {
        const f16x8 va0 = *(const f16x8*)(gA + k0);
        const f16x8 va1 = *(const f16x8*)(gA + k0 + 16 * 768);
        const f16x8 vb0 = *(const f16x8*)(gB + k0);
        const f16x8 vb1 = *(const f16x8*)(gB + k0 + 16 * 768);
        __syncthreads();
        *(f16x8*)(As + srow * LDA + scol)        = va0;
        *(f16x8*)(As + (srow + 16) * LDA + scol) = va1;
        *(f16x8*)(Bs + srow * LDA + scol)        = vb0;
        *(f16x8*)(Bs + (srow + 16) * LDA + scol) = vb1;
        __syncthreads();
        f16x8 af[4], bf[4];
#pragma unroll
        for (int i = 0; i < 4; i++)
            af[i] = *(const f16x8*)(As + (wr * 64 + i * 16 + l16) * LDA + quad * 8);
#pragma unroll
        for (int i = 0; i < 4; i++)
            bf[i] = *(const f16x8*)(Bs + (wc * 64 + i * 16 + l16) * LDA + quad * 8);
#pragma unroll
        for (int i = 0; i < 4; i++)
#pragma unroll
            for (int j = 0; j < 4; j++)
                acc[i][j] = mfma16(af[i], bf[j], acc[i][j]);
    }

#pragma unroll
    for (int j = 0; j < 4; j++) {
        const int   nj = n0 + wc * 64 + j * 16 + l16;
        const float bb = bias[nj];
#pragma unroll
        for (int i = 0; i < 4; i++) {
            const int mb = m0 + wr * 64 + i * 16 + quad * 4;
#pragma unroll
            for (int r = 0; r < 4; r++)
                out[(mb + r) * 768 + nj] = acc[i][j][r] + bb;
        }
    }
}

// ---------------------------------------------------------------- fused attention
// One block = (b,h, 16 q-rows). Phases:
//  0: rel[q,r] = Q.embK_h  (MFMA, into relw LDS)
//  1: scores = (Q.K^T + rel[clip(k-q)])/8  -> sc LDS (f16)
//  2: row softmax (16 thr/row, shfl reductions), attn back into sc, tail sums
//  3: attn strip -> global fp32 (coalesced float4)
//  4: w[q,r] built into relw from attn strip + tails
//  5: ctx = attn@V^T + w@embV^T (MFMA, V pre-transposed), -> ctx f16
constexpr int SCP = 1032;  // padded score row stride (f16), 16B-multiple

__global__ __launch_bounds__(256) void k_attn(
    const f16* __restrict__ Qh, const f16* __restrict__ Kh, const f16* __restrict__ Vt,
    const f16* __restrict__ embK, const f16* __restrict__ embVt,
    float* __restrict__ attn, f16* __restrict__ ctx) {
    __shared__ __align__(16) f16 sc[16 * SCP];     // 33,024 B
    __shared__ __align__(16) f16 relw[16 * 160];   //  5,120 B
    __shared__ float tails[16][2];

    const int qt = blockIdx.x, bh = blockIdx.y;
    const int b = bh / 12, h = bh % 12;
    const int q0 = qt * 16;
    const int tid = threadIdx.x;
    const int w = tid >> 6, l = tid & 63, quad = l >> 4, l16 = l & 15;

    const f16* Qb = Qh + (bh * 1024 + q0) * 64;
    const f16* Kb = Kh + bh * 1024 * 64;
    const f16* Vb = Vt + bh * 64 * 1024;

    // A-operand frags of Q: A[m=lane&15][k=quad*8+j], two k-steps of 32
    const f16x8 qa0 = *(const f16x8*)(Qb + l16 * 64 + quad * 8);
    const f16x8 qa1 = *(const f16x8*)(Qb + l16 * 64 + 32 + quad * 8);

    // phase 0 ------------------------------------------------------
    for (int nf = w; nf < 9; nf += 4) {
        const int r0 = nf * 16;
        int rr = r0 + l16; if (rr > 128) rr = 128;  // clamp OOB rows
        const f16x8 b0 = *(const f16x8*)(embK + rr * 768 + h * 64 + quad * 8);
        const f16x8 b1 = *(const f16x8*)(embK + rr * 768 + h * 64 + 32 + quad * 8);
        f32x4 a = {};
        a = mfma16(qa0, b0, a);
        a = mfma16(qa1, b1, a);
#pragma unroll
        for (int r = 0; r < 4; r++)
            relw[(quad * 4 + r) * 160 + r0 + l16] = (f16)a[r];
    }
    __syncthreads();

    // phase 1 ------------------------------------------------------
    for (int nf = 0; nf < 16; nf++) {
        const int kc = w * 256 + nf * 16;
        const f16x8 b0 = *(const f16x8*)(Kb + (kc + l16) * 64 + quad * 8);
        const f16x8 b1 = *(const f16x8*)(Kb + (kc + l16) * 64 + 32 + quad * 8);
        f32x4 a = {};
        a = mfma16(qa0, b0, a);
        a = mfma16(qa1, b1, a);
        const int kg = kc + l16;
#pragma unroll
        for (int r = 0; r < 4; r++) {
            const int row = quad * 4 + r;
            int d = kg - (q0 + row);
            d = (d < -64) ? -64 : (d > 64) ? 64 : d;
            const float s = (a[r] + (float)relw[row * 160 + d + 64]) * 0.125f;
            sc[row * SCP + kg] = (f16)s;
        }
    }
    __syncthreads();

    // phase 2 ------------------------------------------------------
    {
        const int row = tid >> 4, i = tid & 15;
        const int qg = q0 + row;
        f16* p = sc + row * SCP + i * 64;
        float mx = -1e30f;
        for (int c = 0; c < 64; c++) mx = fmaxf(mx, (float)p[c]);
        for (int o = 1; o < 16; o <<= 1) mx = fmaxf(mx, __shfl_xor(mx, o));
        float sm = 0.f;
        for (int c = 0; c < 64; c++) sm += __expf((float)p[c] - mx);
        for (int o = 1; o < 16; o <<= 1) sm += __shfl_xor(sm, o);
        const float inv = 1.f / sm;
        float t0 = 0.f, t1 = 0.f;
        const int cb = i * 64;
        for (int c = 0; c < 64; c++) {
            const float a = __expf((float)p[c] - mx) * inv;
            p[c] = (f16)a;
            const int kg = cb + c;
            if (kg <= qg - 64) t0 += a;
            if (kg >= qg + 64) t1 += a;
        }
        for (int o = 1; o < 16; o <<= 1) {
            t0 += __shfl_xor(t0, o);
            t1 += __shfl_xor(t1, o);
        }
        if (i == 0) { tails[row][0] = t0; tails[row][1] = t1; }
    }
    __syncthreads();

    // phase 3: attn -> global (wave w owns rows 4w..4w+3) ----------
    {
        float* ab = attn + ((long)bh * 1024 + q0) * 1024;
#pragma unroll
        for (int rr = 0; rr < 4; rr++) {
            const int row = w * 4 + rr;
            const f16* p = sc + row * SCP;
            float* o = ab + (long)row * 1024;
#pragma unroll
            for (int jj = 0; jj < 4; jj++) {
                const int c = jj * 256 + l * 4;
                const f16x4 v = *(const f16x4*)(p + c);
                *(float4*)(o + c) =
                    make_float4((float)v[0], (float)v[1], (float)v[2], (float)v[3]);
            }
        }
    }
    // phase 4: build w into relw -----------------------------------
    for (int idx = tid; idx < 16 * 160; idx += 256) {
        const int row = idx / 160, r = idx - row * 160;
        float v = 0.f;
        if (r == 0) v = tails[row][0];
        else if (r == 128) v = tails[row][1];
        else if (r < 128) {
            const int col = q0 + row + r - 64;
            if (col >= 0 && col < 1024) v = (float)sc[row * SCP + col];
        }
        relw[idx] = (f16)v;
    }
    __syncthreads();

    // phase 5: PV + relV (wave w -> dh block w*16) -----------------
    {
        f32x4 a = {};
        const f16* vrow = Vb + (w * 16 + l16) * 1024;
        for (int ks = 0; ks < 32; ks++) {
            const f16x8 af = *(const f16x8*)(sc + l16 * SCP + ks * 32 + quad * 8);
            const f16x8 bf = *(const f16x8*)(vrow + ks * 32 + quad * 8);
            a = mfma16(af, bf, a);
        }
        const f16* erow = embVt + (h * 64 + w * 16 + l16) * 160;
#pragma unroll
        for (int ks = 0; ks < 5; ks++) {
            const f16x8 af = *(const f16x8*)(relw + l16 * 160 + ks * 32 + quad * 8);
            const f16x8 bf = *(const f16x8*)(erow + ks * 32 + quad * 8);
            a = mfma16(af, bf, a);
        }
#pragma unroll
        for (int r = 0; r < 4; r++) {
            const int qg = q0 + quad * 4 + r;
            ctx[(b * 1024 + qg) * 768 + h * 64 + w * 16 + l16] = (f16)a[r];
        }
    }
}

// ---------------------------------------------------------------- launch
extern "C" void kernel_launch(void* const* d_in, const int* in_sizes, int n_in,
                              void* d_out, int out_size, void* d_ws, size_t ws_size,
                              hipStream_t stream) {
    const float* q_in = (const float*)d_in[0];
    const float* k_in = (const float*)d_in[1];
    const float* v_in = (const float*)d_in[2];
    const float* WQw  = (const float*)d_in[3];
    const float* WQb  = (const float*)d_in[4];
    const float* WKw  = (const float*)d_in[5];
    const float* WKb  = (const float*)d_in[6];
    const float* WVw  = (const float*)d_in[7];
    const float* WVb  = (const float*)d_in[8];
    const float* WOw  = (const float*)d_in[9];
    const float* WOb  = (const float*)d_in[10];
    const float* embK = (const float*)d_in[11];
    const float* embV = (const float*)d_in[12];

    char*  ws  = (char*)d_ws;
    size_t off = 0;
    auto nxt = [&](size_t n) {
        char* p = ws + off;
        off += (n + 255) & ~(size_t)255;
        return p;
    };
    f16* qb    = (f16*)nxt(3145728 * 2);
    f16* kb    = (f16*)nxt(3145728 * 2);
    f16* vb    = (f16*)nxt(3145728 * 2);
    f16* Wqb   = (f16*)nxt(589824 * 2);
    f16* Wkb   = (f16*)nxt(589824 * 2);
    f16* Wvb   = (f16*)nxt(589824 * 2);
    f16* Wob   = (f16*)nxt(589824 * 2);
    f16* embKb = (f16*)nxt(99072 * 2);
    f16* embVt = (f16*)nxt(122880 * 2);
    f16* Qh    = (f16*)nxt(3145728 * 2);
    f16* Kh    = (f16*)nxt(3145728 * 2);
    f16* Vt    = (f16*)nxt(3145728 * 2);
    f16* ctx   = (f16*)nxt(3145728 * 2);
    (void)ws_size; (void)in_sizes; (void)n_in; (void)out_size;

    ConvArgs ca;
    ca.src[0] = q_in; ca.src[1] = k_in; ca.src[2] = v_in;
    ca.src[3] = WQw;  ca.src[4] = WKw;  ca.src[5] = WVw;
    ca.src[6] = WOw;  ca.src[7] = embK;
    ca.dst[0] = qb;   ca.dst[1] = kb;   ca.dst[2] = vb;
    ca.dst[3] = Wqb;  ca.dst[4] = Wkb;  ca.dst[5] = Wvb;
    ca.dst[6] = Wob;  ca.dst[7] = embKb;

    k_convert<<<dim3(2048), dim3(256), 0, stream>>>(ca);
    k_embvt<<<dim3(480), dim3(256), 0, stream>>>(embV, embVt);
    k_gemm_qkv<<<dim3(32, 18), dim3(256), 0, stream>>>(
        qb, kb, vb, Wqb, Wkb, Wvb, WQb, WKb, WVb, Qh, Kh, Vt);
    float* attn = (float*)d_out + 3145728;
    k_attn<<<dim3(64, 48), dim3(256), 0, stream>>>(Qh, Kh, Vt, embKb, embVt, attn, ctx);
    k_gemm_out<<<dim3(32, 6), dim3(256), 0, stream>>>(ctx, Wob, WOb, (float*)d_out);
}

// Round 3
// 398.196 us; speedup vs baseline: 1.0444x; 1.0444x over previous
//
#include <hip/hip_runtime.h>

typedef _Float16 f16;
typedef _Float16 f16x4 __attribute__((ext_vector_type(4)));
typedef _Float16 f16x8 __attribute__((ext_vector_type(8)));
typedef float    f32x4 __attribute__((ext_vector_type(4)));

#define DEV static __device__ __forceinline__

DEV f32x4 mfma16(f16x8 a, f16x8 b, f32x4 c) {
    return __builtin_amdgcn_mfma_f32_16x16x32_f16(a, b, c, 0, 0, 0);
}

// async global->LDS, 16B per lane, dest = wave-uniform base + lane*16
DEV void gload16(const f16* g, f16* l) {
    __builtin_amdgcn_global_load_lds(
        (const __attribute__((address_space(1))) unsigned int*)g,
        (__attribute__((address_space(3))) unsigned int*)l,
        16, 0, 0);
}

// ---------------------------------------------------------------- constants
// B=4, S=1024, D=768, H=12, DH=64, R=129 (padded to 160 for k-steps of 32)

// ---------------------------------------------------------------- convert
struct ConvArgs {
    const float* src[8];
    f16*         dst[8];
};

__global__ __launch_bounds__(256) void k_convert(ConvArgs a) {
    const int seg[9] = {0, 786432, 1572864, 2359296, 2506752, 2654208,
                        2801664, 2949120, 2973888};
    for (int i = blockIdx.x * 256 + threadIdx.x; i < 2973888; i += gridDim.x * 256) {
        int s = 0;
        while (i >= seg[s + 1]) s++;
        const int j = i - seg[s];
        const float4 v = ((const float4*)a.src[s])[j];
        f16x4 o;
        o[0] = (f16)v.x; o[1] = (f16)v.y; o[2] = (f16)v.z; o[3] = (f16)v.w;
        ((f16x4*)a.dst[s])[j] = o;
    }
}

// embVt[h][dh][r] = embV[r, h*64+dh] for r<129 else 0   (12*64*160 elements)
__global__ __launch_bounds__(256) void k_embvt(const float* __restrict__ embV,
                                               f16* __restrict__ dst) {
    const int idx = blockIdx.x * 256 + threadIdx.x;
    if (idx >= 12 * 64 * 160) return;
    const int r  = idx % 160;
    const int dh = (idx / 160) % 64;
    const int h  = idx / (160 * 64);
    float v = 0.f;
    if (r < 129) v = embV[r * 768 + h * 64 + dh];
    dst[idx] = (f16)v;
}

// ---------------------------------------------------------------- GEMM core
// 128x128 tile, BK=32 (64B rows in LDS, no pad). Async global_load_lds
// staging with XOR chunk swizzle: slot (r,c) holds global chunk c^s(r),
// s(r)=((r)^(r>>2))&3  -> reader chunk = quad ^ s(l16); max 2-way bank
// aliasing (free). Each wave stages its 32 rows of A and B (2 instrs each).
// NOTE: all macro locals must avoid kernel-parameter names (xq bug, round 2).
#define GEMM_TILE_BODY(X, W)                                                   \
    const int tid = threadIdx.x;                                               \
    const int w = tid >> 6, l = tid & 63, quad = l >> 4, l16 = l & 15;         \
    const int wr = w >> 1, wc = w & 1;                                         \
    const int rl = l >> 2, cc = l & 3;                                         \
    const int csrc = (cc ^ ((rl ^ (rl >> 2)) & 3)) * 8;                        \
    const f16* gA = (X) + (size_t)(m0 + w * 32 + rl) * 768 + csrc;             \
    const f16* gB = (W) + (size_t)(n0 + w * 32 + rl) * 768 + csrc;             \
    f16* lA0 = As + (w * 32) * 32;                                             \
    f16* lA1 = As + (w * 32 + 16) * 32;                                        \
    f16* lB0 = Bs + (w * 32) * 32;                                             \
    f16* lB1 = Bs + (w * 32 + 16) * 32;                                        \
    const int xsw = (quad ^ ((l16 ^ (l16 >> 2)) & 3)) * 8;                     \
    f32x4 acc[4][4] = {};                                                      \
    for (int k0 = 0; k0 < 768; k0 += 32) {                                     \
        __syncthreads();                                                       \
        gload16(gA + k0, lA0);                                                 \
        gload16(gA + k0 + 16 * 768, lA1);                                      \
        gload16(gB + k0, lB0);                                                 \
        gload16(gB + k0 + 16 * 768, lB1);                                      \
        __syncthreads();                                                       \
        f16x8 af[4], bf[4];                                                    \
        _Pragma("unroll") for (int i = 0; i < 4; i++)                          \
            af[i] = *(const f16x8*)(As + (wr * 64 + i * 16 + l16) * 32 + xsw); \
        _Pragma("unroll") for (int i = 0; i < 4; i++)                          \
            bf[i] = *(const f16x8*)(Bs + (wc * 64 + i * 16 + l16) * 32 + xsw); \
        _Pragma("unroll") for (int i = 0; i < 4; i++)                          \
            _Pragma("unroll") for (int j = 0; j < 4; j++)                      \
                acc[i][j] = mfma16(af[i], bf[j], acc[i][j]);                   \
    }

// ---------------------------------------------------------------- QKV GEMM
__global__ __launch_bounds__(256) void k_gemm_qkv(
    const f16* __restrict__ xq, const f16* __restrict__ xk, const f16* __restrict__ xv,
    const f16* __restrict__ wq, const f16* __restrict__ wk, const f16* __restrict__ wv,
    const float* __restrict__ bq, const float* __restrict__ bk, const float* __restrict__ bv,
    f16* __restrict__ Qh, f16* __restrict__ Kh, f16* __restrict__ Vt) {
    __shared__ __align__(16) f16 As[128 * 32];
    __shared__ __align__(16) f16 Bs[128 * 32];

    const int t  = blockIdx.y / 6;           // 0:Q 1:K 2:V
    const int n0 = (blockIdx.y % 6) * 128;   // within 768
    const int m0 = blockIdx.x * 128;
    const f16*   X    = (t == 0) ? xq : (t == 1) ? xk : xv;
    const f16*   W    = (t == 0) ? wq : (t == 1) ? wk : wv;
    const float* bias = (t == 0) ? bq : (t == 1) ? bk : bv;

    GEMM_TILE_BODY(X, W)

    // epilogue: C/D layout col=lane&15, row=quad*4+reg
#pragma unroll
    for (int j = 0; j < 4; j++) {
        const int   nj = n0 + wc * 64 + j * 16 + l16;  // 0..767
        const float bb = bias[nj];
        const int   h = nj >> 6, dh = nj & 63;
#pragma unroll
        for (int i = 0; i < 4; i++) {
            const int mb = m0 + wr * 64 + i * 16 + quad * 4;
            const int b = mb >> 10, s = mb & 1023;
            if (t < 2) {
                f16* dst = (t == 0) ? Qh : Kh;
                const int base = ((b * 12 + h) * 1024 + s) * 64 + dh;
#pragma unroll
                for (int r = 0; r < 4; r++)
                    dst[base + r * 64] = (f16)(acc[i][j][r] + bb);
            } else {
                f16x4 pk;
#pragma unroll
                for (int r = 0; r < 4; r++) pk[r] = (f16)(acc[i][j][r] + bb);
                *(f16x4*)(Vt + ((b * 12 + h) * 64 + dh) * 1024 + s) = pk;
            }
        }
    }
}

// ---------------------------------------------------------------- out GEMM
__global__ __launch_bounds__(256) void k_gemm_out(
    const f16* __restrict__ Xin, const f16* __restrict__ Win,
    const float* __restrict__ bias, float* __restrict__ out) {
    __shared__ __align__(16) f16 As[128 * 32];
    __shared__ __align__(16) f16 Bs[128 * 32];

    const int n0 = blockIdx.y * 128;
    const int m0 = blockIdx.x * 128;

    GEMM_TILE_BODY(Xin, Win)

#pragma unroll
    for (int j = 0; j < 4; j++) {
        const int   nj = n0 + wc * 64 + j * 16 + l16;
        const float bb = bias[nj];
#pragma unroll
        for (int i = 0; i < 4; i++) {
            const int mb = m0 + wr * 64 + i * 16 + quad * 4;
#pragma unroll
            for (int r = 0; r < 4; r++)
                out[(size_t)(mb + r) * 768 + nj] = acc[i][j][r] + bb;
        }
    }
}

// ---------------------------------------------------------------- fused attention
// One block = (b,h, 16 q-rows). No-max softmax fused into score phase:
//  0: rel[q,r] = Q.embK_h  (MFMA -> relw LDS, raw)
//  1: e = exp((Q.K^T + rel[clip])/8) -> sc LDS (f16, unnormalized);
//     row-sums + 2 tail-sums accumulated in registers
//  2: shfl+LDS reduce -> invs[16], raw tails
//  3: attn strip -> global fp32 = sc * inv   (coalesced float4)
//  4: w[q,r] built raw into relw from sc + tails
//  5: ctx = (attnU@V^T + wU@embV^T) * inv  (MFMA, V pre-transposed)
constexpr int SCP = 1032;  // padded score row stride (f16), 16B-multiple

__global__ __launch_bounds__(256) void k_attn(
    const f16* __restrict__ Qh, const f16* __restrict__ Kh, const f16* __restrict__ Vt,
    const f16* __restrict__ embK, const f16* __restrict__ embVt,
    float* __restrict__ attn, f16* __restrict__ ctx) {
    __shared__ __align__(16) f16 sc[16 * SCP];     // 33,024 B
    __shared__ __align__(16) f16 relw[16 * 160];   //  5,120 B
    __shared__ float red[3][4][16];                // sum,t0,t1 per wave per row
    __shared__ float invs[16], tl0[16], tl1[16];

    const int qt = blockIdx.x, bh = blockIdx.y;
    const int b = bh / 12, h = bh % 12;
    const int q0 = qt * 16;
    const int tid = threadIdx.x;
    const int w = tid >> 6, l = tid & 63, quad = l >> 4, l16 = l & 15;

    const f16* Qb = Qh + (bh * 1024 + q0) * 64;
    const f16* Kb = Kh + bh * 1024 * 64;
    const f16* Vb = Vt + bh * 64 * 1024;

    // A-operand frags of Q: A[m=lane&15][k=quad*8+j], two k-steps of 32
    const f16x8 qa0 = *(const f16x8*)(Qb + l16 * 64 + quad * 8);
    const f16x8 qa1 = *(const f16x8*)(Qb + l16 * 64 + 32 + quad * 8);

    // phase 0 ------------------------------------------------------
    for (int nf = w; nf < 9; nf += 4) {
        const int r0 = nf * 16;
        int rr = r0 + l16; if (rr > 128) rr = 128;
        const f16x8 b0 = *(const f16x8*)(embK + rr * 768 + h * 64 + quad * 8);
        const f16x8 b1 = *(const f16x8*)(embK + rr * 768 + h * 64 + 32 + quad * 8);
        f32x4 a = {};
        a = mfma16(qa0, b0, a);
        a = mfma16(qa1, b1, a);
#pragma unroll
        for (int r = 0; r < 4; r++)
            relw[(quad * 4 + r) * 160 + r0 + l16] = (f16)a[r];
    }
    __syncthreads();

    // phase 1 ------------------------------------------------------
    float rs[4] = {0.f, 0.f, 0.f, 0.f};
    float rt0[4] = {0.f, 0.f, 0.f, 0.f};
    float rt1[4] = {0.f, 0.f, 0.f, 0.f};
    for (int nf = 0; nf < 16; nf++) {
        const int kc = w * 256 + nf * 16;
        const f16x8 b0 = *(const f16x8*)(Kb + (kc + l16) * 64 + quad * 8);
        const f16x8 b1 = *(const f16x8*)(Kb + (kc + l16) * 64 + 32 + quad * 8);
        f32x4 a = {};
        a = mfma16(qa0, b0, a);
        a = mfma16(qa1, b1, a);
        const int kg = kc + l16;
#pragma unroll
        for (int r = 0; r < 4; r++) {
            const int row = quad * 4 + r;
            const int qg = q0 + row;
            int d = kg - qg;
            d = (d < -64) ? -64 : (d > 64) ? 64 : d;
            const float s = (a[r] + (float)relw[row * 160 + d + 64]) * 0.125f;
            const float e = __expf(s);
            sc[row * SCP + kg] = (f16)e;
            rs[r] += e;
            rt0[r] += (kg <= qg - 64) ? e : 0.f;
            rt1[r] += (kg >= qg + 64) ? e : 0.f;
        }
    }
#pragma unroll
    for (int r = 0; r < 4; r++)
        for (int o = 1; o < 16; o <<= 1) {
            rs[r]  += __shfl_xor(rs[r], o);
            rt0[r] += __shfl_xor(rt0[r], o);
            rt1[r] += __shfl_xor(rt1[r], o);
        }
    if (l16 == 0) {
#pragma unroll
        for (int r = 0; r < 4; r++) {
            red[0][w][quad * 4 + r] = rs[r];
            red[1][w][quad * 4 + r] = rt0[r];
            red[2][w][quad * 4 + r] = rt1[r];
        }
    }
    __syncthreads();
    if (tid < 16) {
        const float s = red[0][0][tid] + red[0][1][tid] + red[0][2][tid] + red[0][3][tid];
        invs[tid] = 1.f / s;
        tl0[tid] = red[1][0][tid] + red[1][1][tid] + red[1][2][tid] + red[1][3][tid];
        tl1[tid] = red[2][0][tid] + red[2][1][tid] + red[2][2][tid] + red[2][3][tid];
    }
    __syncthreads();

    // phase 3: attn -> global (wave w owns rows 4w..4w+3) ----------
    {
        float* ab = attn + ((long)bh * 1024 + q0) * 1024;
#pragma unroll
        for (int rr = 0; rr < 4; rr++) {
            const int row = w * 4 + rr;
            const float inv = invs[row];
            const f16* p = sc + row * SCP;
            float* o = ab + (long)row * 1024;
#pragma unroll
            for (int jj = 0; jj < 4; jj++) {
                const int c = jj * 256 + l * 4;
                const f16x4 v = *(const f16x4*)(p + c);
                *(float4*)(o + c) = make_float4((float)v[0] * inv, (float)v[1] * inv,
                                                (float)v[2] * inv, (float)v[3] * inv);
            }
        }
    }
    // phase 4: build raw w into relw -------------------------------
    for (int idx = tid; idx < 16 * 160; idx += 256) {
        const int row = idx / 160, r = idx - row * 160;
        float v = 0.f;
        if (r == 0) v = tl0[row];
        else if (r == 128) v = tl1[row];
        else if (r < 128) {
            const int col = q0 + row + r - 64;
            if (col >= 0 && col < 1024) v = (float)sc[row * SCP + col];
        }
        relw[idx] = (f16)v;
    }
    __syncthreads();

    // phase 5: PV + relV (wave w -> dh block w*16) -----------------
    {
        f32x4 a = {};
        const f16* vrow = Vb + (w * 16 + l16) * 1024;
        for (int ks = 0; ks < 32; ks++) {
            const f16x8 af = *(const f16x8*)(sc + l16 * SCP + ks * 32 + quad * 8);
            const f16x8 bf = *(const f16x8*)(vrow + ks * 32 + quad * 8);
            a = mfma16(af, bf, a);
        }
        const f16* erow = embVt + (h * 64 + w * 16 + l16) * 160;
#pragma unroll
        for (int ks = 0; ks < 5; ks++) {
            const f16x8 af = *(const f16x8*)(relw + l16 * 160 + ks * 32 + quad * 8);
            const f16x8 bf = *(const f16x8*)(erow + ks * 32 + quad * 8);
            a = mfma16(af, bf, a);
        }
#pragma unroll
        for (int r = 0; r < 4; r++) {
            const int row = quad * 4 + r;
            const int qg = q0 + row;
            ctx[(b * 1024 + qg) * 768 + h * 64 + w * 16 + l16] = (f16)(a[r] * invs[row]);
        }
    }
}

// ---------------------------------------------------------------- launch
extern "C" void kernel_launch(void* const* d_in, const int* in_sizes, int n_in,
                              void* d_out, int out_size, void* d_ws, size_t ws_size,
                              hipStream_t stream) {
    const float* q_in = (const float*)d_in[0];
    const float* k_in = (const float*)d_in[1];
    const float* v_in = (const float*)d_in[2];
    const float* WQw  = (const float*)d_in[3];
    const float* WQb  = (const float*)d_in[4];
    const float* WKw  = (const float*)d_in[5];
    const float* WKb  = (const float*)d_in[6];
    const float* WVw  = (const float*)d_in[7];
    const float* WVb  = (const float*)d_in[8];
    const float* WOw  = (const float*)d_in[9];
    const float* WOb  = (const float*)d_in[10];
    const float* embK = (const float*)d_in[11];
    const float* embV = (const float*)d_in[12];

    char*  ws  = (char*)d_ws;
    size_t off = 0;
    auto nxt = [&](size_t n) {
        char* p = ws + off;
        off += (n + 255) & ~(size_t)255;
        return p;
    };
    f16* qb    = (f16*)nxt(3145728 * 2);
    f16* kb    = (f16*)nxt(3145728 * 2);
    f16* vb    = (f16*)nxt(3145728 * 2);
    f16* Wqb   = (f16*)nxt(589824 * 2);
    f16* Wkb   = (f16*)nxt(589824 * 2);
    f16* Wvb   = (f16*)nxt(589824 * 2);
    f16* Wob   = (f16*)nxt(589824 * 2);
    f16* embKb = (f16*)nxt(99072 * 2);
    f16* embVt = (f16*)nxt(122880 * 2);
    f16* Qh    = (f16*)nxt(3145728 * 2);
    f16* Kh    = (f16*)nxt(3145728 * 2);
    f16* Vt    = (f16*)nxt(3145728 * 2);
    f16* ctx   = (f16*)nxt(3145728 * 2);
    (void)ws_size; (void)in_sizes; (void)n_in; (void)out_size;

    ConvArgs ca;
    ca.src[0] = q_in; ca.src[1] = k_in; ca.src[2] = v_in;
    ca.src[3] = WQw;  ca.src[4] = WKw;  ca.src[5] = WVw;
    ca.src[6] = WOw;  ca.src[7] = embK;
    ca.dst[0] = qb;   ca.dst[1] = kb;   ca.dst[2] = vb;
    ca.dst[3] = Wqb;  ca.dst[4] = Wkb;  ca.dst[5] = Wvb;
    ca.dst[6] = Wob;  ca.dst[7] = embKb;

    k_convert<<<dim3(2048), dim3(256), 0, stream>>>(ca);
    k_embvt<<<dim3(480), dim3(256), 0, stream>>>(embV, embVt);
    k_gemm_qkv<<<dim3(32, 18), dim3(256), 0, stream>>>(
        qb, kb, vb, Wqb, Wkb, Wvb, WQb, WKb, WVb, Qh, Kh, Vt);
    float* attn = (float*)d_out + 3145728;
    k_attn<<<dim3(64, 48), dim3(256), 0, stream>>>(Qh, Kh, Vt, embKb, embVt, attn, ctx);
    k_gemm_out<<<dim3(32, 6), dim3(256), 0, stream>>>(ctx, Wob, WOb, (float*)d_out);
}